// Round 4
// baseline (144.497 us; speedup 1.0000x reference)
//
#include <hip/hip_runtime.h>
#include <math.h>

#define A_N 2048
#define NLAYERS 2057
#define NCH 2049                  // chunk 0 = block 0 (middle), 1..2048 = experts

// ws layout (float offsets)
#define PART_OFF  0               // 2049*256 = 524544
#define PART2_OFF 524544          // 64*256 = 16384
#define GSUM_OFF  540928
#define WSUM_OFF  540929
#define DUMMY_OFF 540932          // 256 floats, prewarm sink (never read)

// ---- helpers ----

// softmax-2 head: dest[0..1] = softmax(sx @ W2 + b2) * scale   (256 threads)
__device__ __forceinline__ void head256(const float* sx, float* r0, float* r1,
                                        const float* W2, const float* b2,
                                        float scale, float* dest, int t)
{
    float xv = sx[t];
    r0[t] = xv * W2[2*t];
    r1[t] = xv * W2[2*t+1];
    __syncthreads();
    for (int s = 128; s > 0; s >>= 1) {
        if (t < s) { r0[t] += r0[t+s]; r1[t] += r1[t+s]; }
        __syncthreads();
    }
    if (t == 0) {
        float o0 = r0[0] + b2[0], o1 = r1[0] + b2[1];
        float m  = fmaxf(o0, o1);
        float e0 = expf(o0 - m), e1 = expf(o1 - m);
        float inv = scale / (e0 + e1);
        dest[0] = e0 * inv;
        dest[1] = e1 * inv;
    }
    __syncthreads();
}

// sx = relu(sx @ W + b), W row-major [256][256]. 256 threads, wave-K-split:
// wave w owns k in [w*64, w*64+64); lane l owns outputs [4l, 4l+4). float4 loads,
// 16 in flight per thread -> ~64 KB in flight per block (vs 16 KB scalar form).
__device__ __forceinline__ void mv256_ks(float* sx, float (*sacc)[256],
                                         const float* __restrict__ W,
                                         const float* __restrict__ b, int t)
{
    int w = t >> 6, l = t & 63;
    const float4* Wv = (const float4*)W;
    float4 acc = {0.f, 0.f, 0.f, 0.f};
    #pragma unroll 16
    for (int kk = 0; kk < 64; ++kk) {
        int k = w*64 + kk;
        float xv = sx[k];                 // wave-uniform LDS broadcast
        float4 wv = Wv[k*64 + l];         // wave reads 1KB contiguous of row k
        acc.x += xv*wv.x; acc.y += xv*wv.y; acc.z += xv*wv.z; acc.w += xv*wv.w;
    }
    sacc[w][4*l+0] = acc.x; sacc[w][4*l+1] = acc.y;
    sacc[w][4*l+2] = acc.z; sacc[w][4*l+3] = acc.w;
    __syncthreads();
    float v = fmaxf(sacc[0][t] + sacc[1][t] + sacc[2][t] + sacc[3][t] + b[t], 0.f);
    sx[t] = v;
    __syncthreads();
}

// ---- kernel 1: everything except end stack (2049 blocks x 256) ----
__global__ __launch_bounds__(256) void k_main(
    const float* __restrict__ X, const int* __restrict__ Xm,
    const float* __restrict__ bfv,
    const float* __restrict__ Wbf, const float* __restrict__ bbf,
    const float* __restrict__ Wbr, const float* __restrict__ bbr,
    const float* __restrict__ Wbo, const float* __restrict__ bbo,
    const float* __restrict__ Wm, const float* __restrict__ bm,
    const float* __restrict__ Wmo, const float* __restrict__ bmo,
    const float* __restrict__ Wa, const float* __restrict__ ba,
    const float* __restrict__ Wao, const float* __restrict__ bao,
    const float* __restrict__ Wef, const float* __restrict__ lw,
    const float* __restrict__ Wer, const float* __restrict__ Weo,
    const float* __restrict__ bef, const float* __restrict__ ber,
    const float* __restrict__ beo,
    float* __restrict__ out, float* __restrict__ ws)
{
    __shared__ float sg[256];        // vector feeding this block's We_first rows
    __shared__ float sacc[4][256];   // scratch / reductions
    int b = blockIdx.x, t = threadIdx.x;
    float* part = ws + PART_OFF;

    if (b == 0) {
        // ---- mask-weighted sums ----
        float ga = 0.f;
        for (int a = t; a < A_N; a += 256) if (Xm[a] != 0) ga += lw[4 + a];
        sacc[0][t] = ga; __syncthreads();
        for (int s = 128; s > 0; s >>= 1) { if (t < s) sacc[0][t] += sacc[0][t+s]; __syncthreads(); }
        if (t == 0) {
            float gaux = sacc[0][0];
            ws[GSUM_OFF] = gaux + lw[2056];
            ws[WSUM_OFF] = lw[0]+lw[1]+lw[2]+lw[3] + gaux
                         + lw[2052]+lw[2053]+lw[2054]+lw[2055]+lw[2056];
        }
        __syncthreads();

        // ---- base stack ----
        sg[t] = fmaxf(bfv[0] * Wbf[t] + bbf[t], 0.f);
        __syncthreads();
        head256(sg, sacc[0], sacc[1], Wbo, bbo, lw[0], out + 2, t);
        for (int i = 0; i < 3; ++i) {
            mv256_ks(sg, sacc, Wbr + i*65536, bbr + i*256, t);
            head256(sg, sacc[0], sacc[1], Wbo + (i+1)*512, bbo + (i+1)*2,
                    lw[i+1], out + 2 + (i+1)*2, t);
        }
        // ---- middle ----
        mv256_ks(sg, sacc, Wm, bm, t);
        head256(sg, sacc[0], sacc[1], Wmo, bmo, lw[2056], out + 2 + 2056*2, t);
        sg[t] *= lw[2056];           // middle * lw (gsum divide deferred)
        __syncthreads();
    } else {
        int e = b - 1;
        if (Xm[e] == 0) {
            if (t == 0) { out[2 + (4+e)*2] = 0.f; out[2 + (4+e)*2 + 1] = 0.f; }
            // ---- prewarm end-stack weights into L3 for k_end (e<256 only) ----
            if (e < 256) {
                int s = e & 15;
                const float4* p = (const float4*)Wer + s*3072;   // 48KB slice
                float4 z = {0.f,0.f,0.f,0.f};
                #pragma unroll 12
                for (int i = t; i < 3072; i += 256) {
                    float4 v = p[i];
                    z.x += v.x; z.y += v.y; z.z += v.z; z.w += v.w;
                }
                if (s == 0) {
                    const float4* q = (const float4*)Weo;
                    #pragma unroll 2
                    for (int i = t; i < 512; i += 256) { float4 v = q[i]; z.x += v.x + v.y + v.z + v.w; }
                    if (t < 64)  { float4 v = ((const float4*)bef)[t]; z.y += v.x+v.y+v.z+v.w; }
                    if (t < 192) { float4 v = ((const float4*)ber)[t]; z.z += v.x+v.y+v.z+v.w; }
                    if (t < 2)   { float4 v = ((const float4*)beo)[t]; z.w += v.x+v.y+v.z+v.w; }
                }
                if (t == 0) ws[DUMMY_OFF + e] = z.x + z.y + z.z + z.w;  // keep loads live
                else if (z.x + z.y + z.z + z.w == 1e30f) ws[DUMMY_OFF] = 0.f; // never true
            }
            return;                  // k_red skips this part row via Xm
        }
        float xv = X[e];
        float w  = lw[4 + e];
        float h  = fmaxf(xv * Wa[e*256 + t] + ba[e*256 + t], 0.f);
        float2 wo = *(const float2*)&Wao[(size_t)e*512 + 2*t];
        sacc[0][t] = h * wo.x;
        sacc[1][t] = h * wo.y;
        sg[t] = h * w;               // u = h*mask*lw (mask==1 here)
        __syncthreads();
        for (int s = 128; s > 0; s >>= 1) {
            if (t < s) { sacc[0][t] += sacc[0][t+s]; sacc[1][t] += sacc[1][t+s]; }
            __syncthreads();
        }
        if (t == 0) {
            float o0 = sacc[0][0] + bao[2*e], o1 = sacc[1][0] + bao[2*e+1];
            float m  = fmaxf(o0, o1);
            float e0 = expf(o0 - m), e1 = expf(o1 - m);
            float inv = w / (e0 + e1);   // * lw * mask; /wsum deferred
            out[2 + (4+e)*2]     = e0 * inv;
            out[2 + (4+e)*2 + 1] = e1 * inv;
        }
        __syncthreads();
    }

    // ---- partial matvec: 256 rows of We_first for this chunk ----
    size_t rowbase = (b == 0) ? (size_t)A_N * 65536 : (size_t)(b - 1) * 65536;
    int quad = t >> 6, lane = t & 63;
    const float4* Wrow = (const float4*)(Wef + rowbase);
    float4 acc = {0.f, 0.f, 0.f, 0.f};
    #pragma unroll 4
    for (int it = 0; it < 64; ++it) {
        int r = it*4 + quad;
        float gv = sg[r];
        float4 wv = Wrow[(size_t)r*64 + lane];
        acc.x += gv*wv.x; acc.y += gv*wv.y; acc.z += gv*wv.z; acc.w += gv*wv.w;
    }
    sacc[quad][lane*4 + 0] = acc.x;
    sacc[quad][lane*4 + 1] = acc.y;
    sacc[quad][lane*4 + 2] = acc.z;
    sacc[quad][lane*4 + 3] = acc.w;
    __syncthreads();
    part[b*256 + t] = sacc[0][t] + sacc[1][t] + sacc[2][t] + sacc[3][t];
}

// ---- kernel 2: reduce part[2049][256] -> part2[64][256], skipping masked ----
__global__ __launch_bounds__(256) void k_red(const int* __restrict__ Xm,
                                             float* __restrict__ ws)
{
    int r = blockIdx.x, t = threadIdx.x;
    float acc = 0.f;
    for (int b = r; b < NCH; b += 64) {
        if (b == 0 || Xm[b-1] != 0) acc += ws[PART_OFF + b*256 + t];
    }
    ws[PART2_OFF + r*256 + t] = acc;
}

// ---- kernel 3: end stack + final combine (1 block x 1024) ----
__global__ __launch_bounds__(1024) void k_end(
    const float* __restrict__ bef, const float* __restrict__ Wer,
    const float* __restrict__ ber, const float* __restrict__ Weo,
    const float* __restrict__ beo, const float* __restrict__ lw,
    float* __restrict__ out, float* __restrict__ ws)
{
    __shared__ float sx[256];
    __shared__ float sacc16[16][256];     // wave-split partials (also part2 reduce)
    __shared__ float red0[1024], red1[1024];
    __shared__ float endraw[4][2];
    int tid = threadIdx.x;
    int w = tid >> 6, l = tid & 63;       // 16 waves x 64 lanes
    int q = tid >> 8, t = tid & 255;

    // finish reduce: part2[64][256] -> sx[256], /gsum, bias, relu
    float acc = 0.f;
    #pragma unroll 16
    for (int j = 0; j < 16; ++j) acc += ws[PART2_OFF + (q*16 + j)*256 + t];
    sacc16[q][t] = acc;
    __syncthreads();
    float gsum = ws[GSUM_OFF];
    if (tid < 256) {
        float v = sacc16[0][t] + sacc16[1][t] + sacc16[2][t] + sacc16[3][t];
        sx[t] = fmaxf(v / gsum + bef[t], 0.f);
    }
    __syncthreads();

    // softmax-2 head on sx (tid<256 active through 256-wide reduce)
    #define HEAD_G(W2, B2, SCALE, DEST)                                         \
    {                                                                           \
        if (tid < 256) { sacc16[14][tid] = sx[tid]*(W2)[2*tid];                 \
                         sacc16[15][tid] = sx[tid]*(W2)[2*tid+1]; }             \
        __syncthreads();                                                        \
        for (int s = 128; s > 0; s >>= 1) {                                     \
            if (tid < s) { sacc16[14][tid] += sacc16[14][tid+s];                \
                           sacc16[15][tid] += sacc16[15][tid+s]; }              \
            __syncthreads();                                                    \
        }                                                                       \
        if (tid == 0) {                                                         \
            float o0 = sacc16[14][0] + (B2)[0], o1 = sacc16[15][0] + (B2)[1];   \
            float m  = fmaxf(o0, o1);                                           \
            float e0 = expf(o0 - m), e1 = expf(o1 - m);                         \
            float inv = (SCALE) / (e0 + e1);                                    \
            (DEST)[0] = e0 * inv; (DEST)[1] = e1 * inv;                         \
        }                                                                       \
        __syncthreads();                                                        \
    }

    HEAD_G(Weo, beo, lw[2052], &endraw[0][0]);
    for (int i = 0; i < 3; ++i) {
        // 16-way wave-K-split matvec: wave w owns k in [w*16, w*16+16)
        const float4* Wv = (const float4*)(Wer + i*65536);
        float4 a4 = {0.f, 0.f, 0.f, 0.f};
        #pragma unroll 16
        for (int kk = 0; kk < 16; ++kk) {
            int k = w*16 + kk;
            float xv = sx[k];
            float4 wv = Wv[k*64 + l];
            a4.x += xv*wv.x; a4.y += xv*wv.y; a4.z += xv*wv.z; a4.w += xv*wv.w;
        }
        sacc16[w][4*l+0] = a4.x; sacc16[w][4*l+1] = a4.y;
        sacc16[w][4*l+2] = a4.z; sacc16[w][4*l+3] = a4.w;
        __syncthreads();
        if (tid < 256) {
            float v = 0.f;
            #pragma unroll 16
            for (int j = 0; j < 16; ++j) v += sacc16[j][t];
            sx[t] = fmaxf(v + ber[i*256 + t], 0.f);
        }
        __syncthreads();
        HEAD_G(Weo + (i+1)*512, beo + (i+1)*2, lw[2053 + i], &endraw[i+1][0]);
    }

    // rescale all rows by 1/wsum, accumulate final logit
    float invw = 1.f / ws[WSUM_OFF];
    float s0 = 0.f, s1 = 0.f;
    for (int i = tid; i < NLAYERS; i += 1024) {
        float v0, v1;
        if (i >= 2052 && i < 2056) { v0 = endraw[i-2052][0]; v1 = endraw[i-2052][1]; }
        else                        { v0 = out[2 + 2*i];      v1 = out[2 + 2*i + 1]; }
        v0 *= invw; v1 *= invw;
        out[2 + 2*i]     = v0;
        out[2 + 2*i + 1] = v1;
        s0 += v0; s1 += v1;
    }
    red0[tid] = s0; red1[tid] = s1; __syncthreads();
    for (int s = 512; s > 0; s >>= 1) {
        if (tid < s) { red0[tid] += red0[tid+s]; red1[tid] += red1[tid+s]; }
        __syncthreads();
    }
    if (tid == 0) { out[0] = red0[0]; out[1] = red1[0]; }
}

extern "C" void kernel_launch(void* const* d_in, const int* in_sizes, int n_in,
                              void* d_out, int out_size, void* d_ws, size_t ws_size,
                              hipStream_t stream)
{
    const float* X    = (const float*)d_in[0];
    const int*   Xm   = (const int*)  d_in[1];
    const float* bfv  = (const float*)d_in[2];
    const float* Wbf  = (const float*)d_in[3];
    const float* bbf  = (const float*)d_in[4];
    const float* Wbr  = (const float*)d_in[5];
    const float* bbr  = (const float*)d_in[6];
    const float* Wbo  = (const float*)d_in[7];
    const float* bbo  = (const float*)d_in[8];
    const float* Wm   = (const float*)d_in[9];
    const float* bm   = (const float*)d_in[10];
    const float* Wmo  = (const float*)d_in[11];
    const float* bmo  = (const float*)d_in[12];
    const float* Wa   = (const float*)d_in[13];
    const float* ba   = (const float*)d_in[14];
    const float* Wao  = (const float*)d_in[15];
    const float* bao  = (const float*)d_in[16];
    const float* Wef  = (const float*)d_in[17];
    const float* bef  = (const float*)d_in[18];
    const float* Wer  = (const float*)d_in[19];
    const float* ber  = (const float*)d_in[20];
    const float* Weo  = (const float*)d_in[21];
    const float* beo  = (const float*)d_in[22];
    const float* lw   = (const float*)d_in[23];
    float* out = (float*)d_out;
    float* wsf = (float*)d_ws;

    k_main<<<NCH, 256, 0, stream>>>(X, Xm, bfv, Wbf, bbf, Wbr, bbr, Wbo, bbo,
                                    Wm, bm, Wmo, bmo, Wa, ba, Wao, bao,
                                    Wef, lw, Wer, Weo, bef, ber, beo, out, wsf);
    k_red<<<64, 256, 0, stream>>>(Xm, wsf);
    k_end<<<1, 1024, 0, stream>>>(bef, Wer, ber, Weo, beo, lw, out, wsf);
}

// Round 5
// 105.791 us; speedup vs baseline: 1.3659x; 1.3659x over previous
//
#include <hip/hip_runtime.h>
#include <math.h>

#define A_N 2048
#define NLAYERS 2057
#define NCH 2049                  // chunk 0 = block 0 (middle), 1..2048 = experts

// ws layout (float offsets)
#define PART_OFF  0               // 2049*256 = 524544
#define PART2_OFF 524544          // 64*256 = 16384
#define GSUM_OFF  540928
#define WSUM_OFF  540929

// ---- helpers (256-thread sections) ----

// softmax-2 head: dest[0..1] = softmax(sx @ W2 + b2) * scale   (256 threads)
__device__ __forceinline__ void head256(const float* sx, float* r0, float* r1,
                                        const float* W2, const float* b2,
                                        float scale, float* dest, int t)
{
    float xv = sx[t];
    r0[t] = xv * W2[2*t];
    r1[t] = xv * W2[2*t+1];
    __syncthreads();
    for (int s = 128; s > 0; s >>= 1) {
        if (t < s) { r0[t] += r0[t+s]; r1[t] += r1[t+s]; }
        __syncthreads();
    }
    if (t == 0) {
        float o0 = r0[0] + b2[0], o1 = r1[0] + b2[1];
        float m  = fmaxf(o0, o1);
        float e0 = expf(o0 - m), e1 = expf(o1 - m);
        float inv = scale / (e0 + e1);
        dest[0] = e0 * inv;
        dest[1] = e1 * inv;
    }
    __syncthreads();
}

// sx = relu(sx @ W + b), W is [256][256] row-major (256 threads, register-light)
__device__ __forceinline__ void mv256(float* sx, const float* __restrict__ W,
                                      const float* __restrict__ b, int t)
{
    float acc = 0.f;
    #pragma unroll 16
    for (int k = 0; k < 256; ++k) acc += sx[k] * W[k*256 + t];
    acc = fmaxf(acc + b[t], 0.f);
    __syncthreads();
    sx[t] = acc;
    __syncthreads();
}

// pull nf4 float4s at base into L3 (loads kept live via asm consume, no DCE)
__device__ __forceinline__ void warm64k(const float* base, int nf4, int t)
{
    const float4* p = (const float4*)base;
    for (int i = t; i < nf4; i += 256) {
        float4 v = p[i];
        asm volatile("" :: "v"(v.x), "v"(v.y), "v"(v.z), "v"(v.w));
    }
}

// ---- kernel 1: everything except end stack (2049 blocks x 256) ----
// block 0: sums + base stack + middle + middle chunk of We_first
// block 1+e: aux expert e (+ its chunk); blocks 1..34 first warm L3 for the
//            serial chain (block 0) and for k_end.
__global__ __launch_bounds__(256) void k_main(
    const float* __restrict__ X, const int* __restrict__ Xm,
    const float* __restrict__ bfv,
    const float* __restrict__ Wbf, const float* __restrict__ bbf,
    const float* __restrict__ Wbr, const float* __restrict__ bbr,
    const float* __restrict__ Wbo, const float* __restrict__ bbo,
    const float* __restrict__ Wm, const float* __restrict__ bm,
    const float* __restrict__ Wmo, const float* __restrict__ bmo,
    const float* __restrict__ Wa, const float* __restrict__ ba,
    const float* __restrict__ Wao, const float* __restrict__ bao,
    const float* __restrict__ Wef, const float* __restrict__ lw,
    const float* __restrict__ Wer, const float* __restrict__ Weo,
    const float* __restrict__ bef, const float* __restrict__ ber,
    float* __restrict__ out, float* __restrict__ ws)
{
    __shared__ float sg[256];        // vector feeding this block's We_first rows
    __shared__ float sacc[4][256];   // scratch / reductions
    int b = blockIdx.x, t = threadIdx.x;
    float* part = ws + PART_OFF;

    // ---- L3 warming (blocks 1..34), then fall through to normal work ----
    if (b >= 1 && b <= 34) {
        int wi = b - 1;
        if      (wi < 12) warm64k(Wbr + (size_t)wi * 16384, 4096, t);        // 768KB
        else if (wi < 16) warm64k(Wm + (size_t)(wi - 12) * 16384, 4096, t);  // 256KB
        else if (wi < 28) warm64k(Wer + (size_t)(wi - 16) * 16384, 4096, t); // 768KB
        else if (wi == 28) { warm64k(Weo, 512, t); warm64k(Wbo, 512, t); }
        else if (wi == 29) { warm64k(Wmo, 128, t); warm64k(bef, 64, t); warm64k(ber, 192, t); }
        else warm64k(Wef + (size_t)A_N * 65536 + (size_t)(wi - 30) * 16384, 4096, t); // mid chunk
    }

    if (b == 0) {
        // ---- mask-weighted sums ----
        float ga = 0.f;
        for (int a = t; a < A_N; a += 256) if (Xm[a] != 0) ga += lw[4 + a];
        sacc[0][t] = ga; __syncthreads();
        for (int s = 128; s > 0; s >>= 1) { if (t < s) sacc[0][t] += sacc[0][t+s]; __syncthreads(); }
        if (t == 0) {
            float gaux = sacc[0][0];
            ws[GSUM_OFF] = gaux + lw[2056];
            ws[WSUM_OFF] = lw[0]+lw[1]+lw[2]+lw[3] + gaux
                         + lw[2052]+lw[2053]+lw[2054]+lw[2055]+lw[2056];
        }
        __syncthreads();

        // ---- base stack ----
        sg[t] = fmaxf(bfv[0] * Wbf[t] + bbf[t], 0.f);
        __syncthreads();
        head256(sg, sacc[0], sacc[1], Wbo, bbo, lw[0], out + 2, t);
        for (int i = 0; i < 3; ++i) {
            mv256(sg, Wbr + i*65536, bbr + i*256, t);
            head256(sg, sacc[0], sacc[1], Wbo + (i+1)*512, bbo + (i+1)*2,
                    lw[i+1], out + 2 + (i+1)*2, t);
        }
        // ---- middle ----
        mv256(sg, Wm, bm, t);
        head256(sg, sacc[0], sacc[1], Wmo, bmo, lw[2056], out + 2 + 2056*2, t);
        sg[t] *= lw[2056];           // middle * lw (gsum divide deferred)
        __syncthreads();
    } else {
        int e = b - 1;
        if (Xm[e] == 0) {            // masked: skip 256KB chunk (k_red skips row)
            if (t == 0) { out[2 + (4+e)*2] = 0.f; out[2 + (4+e)*2 + 1] = 0.f; }
            return;
        }
        float xv = X[e];
        float w  = lw[4 + e];
        float h  = fmaxf(xv * Wa[e*256 + t] + ba[e*256 + t], 0.f);
        float2 wo = *(const float2*)&Wao[(size_t)e*512 + 2*t];
        sacc[0][t] = h * wo.x;
        sacc[1][t] = h * wo.y;
        sg[t] = h * w;               // u = h*mask*lw (mask==1 here)
        __syncthreads();
        for (int s = 128; s > 0; s >>= 1) {
            if (t < s) { sacc[0][t] += sacc[0][t+s]; sacc[1][t] += sacc[1][t+s]; }
            __syncthreads();
        }
        if (t == 0) {
            float o0 = sacc[0][0] + bao[2*e], o1 = sacc[1][0] + bao[2*e+1];
            float m  = fmaxf(o0, o1);
            float e0 = expf(o0 - m), e1 = expf(o1 - m);
            float inv = w / (e0 + e1);   // * lw * mask; /wsum deferred
            out[2 + (4+e)*2]     = e0 * inv;
            out[2 + (4+e)*2 + 1] = e1 * inv;
        }
        __syncthreads();
    }

    // ---- partial matvec: 256 rows of We_first for this chunk ----
    size_t rowbase = (b == 0) ? (size_t)A_N * 65536 : (size_t)(b - 1) * 65536;
    int quad = t >> 6, lane = t & 63;
    const float4* Wrow = (const float4*)(Wef + rowbase);
    float4 acc = {0.f, 0.f, 0.f, 0.f};
    #pragma unroll 4
    for (int it = 0; it < 64; ++it) {
        int r = it*4 + quad;
        float gv = sg[r];
        float4 wv = Wrow[(size_t)r*64 + lane];
        acc.x += gv*wv.x; acc.y += gv*wv.y; acc.z += gv*wv.z; acc.w += gv*wv.w;
    }
    sacc[quad][lane*4 + 0] = acc.x;
    sacc[quad][lane*4 + 1] = acc.y;
    sacc[quad][lane*4 + 2] = acc.z;
    sacc[quad][lane*4 + 3] = acc.w;
    __syncthreads();
    part[b*256 + t] = sacc[0][t] + sacc[1][t] + sacc[2][t] + sacc[3][t];
}

// ---- kernel 2: reduce part[2049][256] -> part2[64][256], skipping masked ----
__global__ __launch_bounds__(256) void k_red(const int* __restrict__ Xm,
                                             float* __restrict__ ws)
{
    int r = blockIdx.x, t = threadIdx.x;
    float acc = 0.f;
    for (int b = r; b < NCH; b += 64) {
        if (b == 0 || Xm[b-1] != 0) acc += ws[PART_OFF + b*256 + t];
    }
    ws[PART2_OFF + r*256 + t] = acc;
}

// ---- kernel 3: end stack + final combine (1 block x 1024) ----
__global__ __launch_bounds__(1024) void k_end(
    const float* __restrict__ bef, const float* __restrict__ Wer,
    const float* __restrict__ ber, const float* __restrict__ Weo,
    const float* __restrict__ beo, const float* __restrict__ lw,
    float* __restrict__ out, float* __restrict__ ws)
{
    __shared__ float sx[256];
    __shared__ float racc[4][256];
    __shared__ float red0[1024], red1[1024];
    __shared__ float endraw[4][2];
    int tid = threadIdx.x;
    int q = tid >> 8, t = tid & 255;

    // finish reduce: part2[64][256] -> acc[256], /gsum, bias, relu
    float acc = 0.f;
    #pragma unroll
    for (int j = 0; j < 16; ++j) acc += ws[PART2_OFF + (q*16 + j)*256 + t];
    racc[q][t] = acc;
    __syncthreads();
    float gsum = ws[GSUM_OFF];
    if (tid < 256) {
        float v = racc[0][t] + racc[1][t] + racc[2][t] + racc[3][t];
        sx[t] = fmaxf(v / gsum + bef[t], 0.f);
    }
    __syncthreads();

    #define HEAD_G(W2, B2, SCALE, DEST)                                         \
    {                                                                           \
        if (tid < 256) { red0[tid] = sx[tid]*(W2)[2*tid]; red1[tid] = sx[tid]*(W2)[2*tid+1]; } \
        __syncthreads();                                                        \
        for (int s = 128; s > 0; s >>= 1) {                                     \
            if (tid < s) { red0[tid] += red0[tid+s]; red1[tid] += red1[tid+s]; }\
            __syncthreads();                                                    \
        }                                                                       \
        if (tid == 0) {                                                         \
            float o0 = red0[0] + (B2)[0], o1 = red1[0] + (B2)[1];               \
            float m  = fmaxf(o0, o1);                                           \
            float e0 = expf(o0 - m), e1 = expf(o1 - m);                         \
            float inv = (SCALE) / (e0 + e1);                                    \
            (DEST)[0] = e0 * inv; (DEST)[1] = e1 * inv;                         \
        }                                                                       \
        __syncthreads();                                                        \
    }

    HEAD_G(Weo, beo, lw[2052], &endraw[0][0]);
    for (int i = 0; i < 3; ++i) {
        // K-split 4-way, deep unroll for load overlap (L3-warm after k_main)
        const float* Wq = Wer + i*65536 + (q*64)*256;
        float a2 = 0.f;
        #pragma unroll 16
        for (int k = 0; k < 64; ++k) a2 += sx[q*64 + k] * Wq[k*256 + t];
        racc[q][t] = a2;
        __syncthreads();
        if (tid < 256) {
            float v = racc[0][t] + racc[1][t] + racc[2][t] + racc[3][t];
            sx[t] = fmaxf(v + ber[i*256 + t], 0.f);
        }
        __syncthreads();
        HEAD_G(Weo + (i+1)*512, beo + (i+1)*2, lw[2053 + i], &endraw[i+1][0]);
    }

    // rescale all rows by 1/wsum, accumulate final logit
    float invw = 1.f / ws[WSUM_OFF];
    float s0 = 0.f, s1 = 0.f;
    for (int i = tid; i < NLAYERS; i += 1024) {
        float v0, v1;
        if (i >= 2052 && i < 2056) { v0 = endraw[i-2052][0]; v1 = endraw[i-2052][1]; }
        else                        { v0 = out[2 + 2*i];      v1 = out[2 + 2*i + 1]; }
        v0 *= invw; v1 *= invw;
        out[2 + 2*i]     = v0;
        out[2 + 2*i + 1] = v1;
        s0 += v0; s1 += v1;
    }
    red0[tid] = s0; red1[tid] = s1; __syncthreads();
    for (int s = 512; s > 0; s >>= 1) {
        if (tid < s) { red0[tid] += red0[tid+s]; red1[tid] += red1[tid+s]; }
        __syncthreads();
    }
    if (tid == 0) { out[0] = red0[0]; out[1] = red1[0]; }
}

extern "C" void kernel_launch(void* const* d_in, const int* in_sizes, int n_in,
                              void* d_out, int out_size, void* d_ws, size_t ws_size,
                              hipStream_t stream)
{
    const float* X    = (const float*)d_in[0];
    const int*   Xm   = (const int*)  d_in[1];
    const float* bfv  = (const float*)d_in[2];
    const float* Wbf  = (const float*)d_in[3];
    const float* bbf  = (const float*)d_in[4];
    const float* Wbr  = (const float*)d_in[5];
    const float* bbr  = (const float*)d_in[6];
    const float* Wbo  = (const float*)d_in[7];
    const float* bbo  = (const float*)d_in[8];
    const float* Wm   = (const float*)d_in[9];
    const float* bm   = (const float*)d_in[10];
    const float* Wmo  = (const float*)d_in[11];
    const float* bmo  = (const float*)d_in[12];
    const float* Wa   = (const float*)d_in[13];
    const float* ba   = (const float*)d_in[14];
    const float* Wao  = (const float*)d_in[15];
    const float* bao  = (const float*)d_in[16];
    const float* Wef  = (const float*)d_in[17];
    const float* bef  = (const float*)d_in[18];
    const float* Wer  = (const float*)d_in[19];
    const float* ber  = (const float*)d_in[20];
    const float* Weo  = (const float*)d_in[21];
    const float* beo  = (const float*)d_in[22];
    const float* lw   = (const float*)d_in[23];
    float* out = (float*)d_out;
    float* wsf = (float*)d_ws;

    k_main<<<NCH, 256, 0, stream>>>(X, Xm, bfv, Wbf, bbf, Wbr, bbr, Wbo, bbo,
                                    Wm, bm, Wmo, bmo, Wa, ba, Wao, bao,
                                    Wef, lw, Wer, Weo, bef, ber, out, wsf);
    k_red<<<64, 256, 0, stream>>>(Xm, wsf);
    k_end<<<1, 1024, 0, stream>>>(bef, Wer, ber, Weo, beo, lw, out, wsf);
}

// Round 6
// 101.649 us; speedup vs baseline: 1.4215x; 1.0408x over previous
//
#include <hip/hip_runtime.h>
#include <math.h>

#define A_N 2048
#define NLAYERS 2057
#define NCH 2049                  // chunk 0 = block 0 (middle), 1..2048 = experts

// ws layout (float offsets)
#define PART_OFF  0               // 2049*256 = 524544
#define PART2_OFF 524544          // 64*256 = 16384
#define GSUM_OFF  540928
#define WSUM_OFF  540929

// ---- helpers (256-thread sections) ----

// softmax-2 head: dest[0..1] = softmax(sx @ W2 + b2) * scale   (256 threads)
__device__ __forceinline__ void head256(const float* sx, float* r0, float* r1,
                                        const float* W2, const float* b2,
                                        float scale, float* dest, int t)
{
    float xv = sx[t];
    r0[t] = xv * W2[2*t];
    r1[t] = xv * W2[2*t+1];
    __syncthreads();
    for (int s = 128; s > 0; s >>= 1) {
        if (t < s) { r0[t] += r0[t+s]; r1[t] += r1[t+s]; }
        __syncthreads();
    }
    if (t == 0) {
        float o0 = r0[0] + b2[0], o1 = r1[0] + b2[1];
        float m  = fmaxf(o0, o1);
        float e0 = expf(o0 - m), e1 = expf(o1 - m);
        float inv = scale / (e0 + e1);
        dest[0] = e0 * inv;
        dest[1] = e1 * inv;
    }
    __syncthreads();
}

// sx = relu(sx @ W + b), W is [256][256] row-major (256 threads, register-light)
__device__ __forceinline__ void mv256(float* sx, const float* __restrict__ W,
                                      const float* __restrict__ b, int t)
{
    float acc = 0.f;
    #pragma unroll 16
    for (int k = 0; k < 256; ++k) acc += sx[k] * W[k*256 + t];
    acc = fmaxf(acc + b[t], 0.f);
    __syncthreads();
    sx[t] = acc;
    __syncthreads();
}

// pull nf4 float4s at base into L3 (loads kept live via asm consume, no DCE)
__device__ __forceinline__ void warm64k(const float* base, int nf4, int t)
{
    const float4* p = (const float4*)base;
    for (int i = t; i < nf4; i += 256) {
        float4 v = p[i];
        asm volatile("" :: "v"(v.x), "v"(v.y), "v"(v.z), "v"(v.w));
    }
}

// ---- kernel 1: everything except end stack (2049 blocks x 256) ----
__global__ __launch_bounds__(256) void k_main(
    const float* __restrict__ X, const int* __restrict__ Xm,
    const float* __restrict__ bfv,
    const float* __restrict__ Wbf, const float* __restrict__ bbf,
    const float* __restrict__ Wbr, const float* __restrict__ bbr,
    const float* __restrict__ Wbo, const float* __restrict__ bbo,
    const float* __restrict__ Wm, const float* __restrict__ bm,
    const float* __restrict__ Wmo, const float* __restrict__ bmo,
    const float* __restrict__ Wa, const float* __restrict__ ba,
    const float* __restrict__ Wao, const float* __restrict__ bao,
    const float* __restrict__ Wef, const float* __restrict__ lw,
    const float* __restrict__ Wer, const float* __restrict__ Weo,
    const float* __restrict__ bef, const float* __restrict__ ber,
    float* __restrict__ out, float* __restrict__ ws)
{
    __shared__ float sg[256];        // vector feeding this block's We_first rows
    __shared__ float sacc[4][256];   // scratch / reductions
    int b = blockIdx.x, t = threadIdx.x;
    float* part = ws + PART_OFF;

    // ---- L3 warming (blocks 1..34), then fall through to normal work ----
    if (b >= 1 && b <= 34) {
        int wi = b - 1;
        if      (wi < 12) warm64k(Wbr + (size_t)wi * 16384, 4096, t);        // 768KB
        else if (wi < 16) warm64k(Wm + (size_t)(wi - 12) * 16384, 4096, t);  // 256KB
        else if (wi < 28) warm64k(Wer + (size_t)(wi - 16) * 16384, 4096, t); // 768KB
        else if (wi == 28) { warm64k(Weo, 512, t); warm64k(Wbo, 512, t); }
        else if (wi == 29) { warm64k(Wmo, 128, t); warm64k(bef, 64, t); warm64k(ber, 192, t); }
        else warm64k(Wef + (size_t)A_N * 65536 + (size_t)(wi - 30) * 16384, 4096, t); // mid chunk
    }

    if (b == 0) {
        // ---- mask-weighted sums ----
        float ga = 0.f;
        for (int a = t; a < A_N; a += 256) if (Xm[a] != 0) ga += lw[4 + a];
        sacc[0][t] = ga; __syncthreads();
        for (int s = 128; s > 0; s >>= 1) { if (t < s) sacc[0][t] += sacc[0][t+s]; __syncthreads(); }
        if (t == 0) {
            float gaux = sacc[0][0];
            ws[GSUM_OFF] = gaux + lw[2056];
            ws[WSUM_OFF] = lw[0]+lw[1]+lw[2]+lw[3] + gaux
                         + lw[2052]+lw[2053]+lw[2054]+lw[2055]+lw[2056];
        }
        __syncthreads();

        // ---- base stack ----
        sg[t] = fmaxf(bfv[0] * Wbf[t] + bbf[t], 0.f);
        __syncthreads();
        head256(sg, sacc[0], sacc[1], Wbo, bbo, lw[0], out + 2, t);
        for (int i = 0; i < 3; ++i) {
            mv256(sg, Wbr + i*65536, bbr + i*256, t);
            head256(sg, sacc[0], sacc[1], Wbo + (i+1)*512, bbo + (i+1)*2,
                    lw[i+1], out + 2 + (i+1)*2, t);
        }
        // ---- middle ----
        mv256(sg, Wm, bm, t);
        head256(sg, sacc[0], sacc[1], Wmo, bmo, lw[2056], out + 2 + 2056*2, t);
        sg[t] *= lw[2056];           // middle * lw (gsum divide deferred)
        __syncthreads();
    } else {
        int e = b - 1;
        if (Xm[e] == 0) {            // masked: skip 256KB chunk (k_red skips row)
            if (t == 0) { out[2 + (4+e)*2] = 0.f; out[2 + (4+e)*2 + 1] = 0.f; }
            return;
        }
        float xv = X[e];
        float w  = lw[4 + e];
        float h  = fmaxf(xv * Wa[e*256 + t] + ba[e*256 + t], 0.f);
        float2 wo = *(const float2*)&Wao[(size_t)e*512 + 2*t];
        sacc[0][t] = h * wo.x;
        sacc[1][t] = h * wo.y;
        sg[t] = h * w;               // u = h*mask*lw (mask==1 here)
        __syncthreads();
        for (int s = 128; s > 0; s >>= 1) {
            if (t < s) { sacc[0][t] += sacc[0][t+s]; sacc[1][t] += sacc[1][t+s]; }
            __syncthreads();
        }
        if (t == 0) {
            float o0 = sacc[0][0] + bao[2*e], o1 = sacc[1][0] + bao[2*e+1];
            float m  = fmaxf(o0, o1);
            float e0 = expf(o0 - m), e1 = expf(o1 - m);
            float inv = w / (e0 + e1);   // * lw * mask; /wsum deferred
            out[2 + (4+e)*2]     = e0 * inv;
            out[2 + (4+e)*2 + 1] = e1 * inv;
        }
        __syncthreads();
    }

    // ---- partial matvec: 256 rows of We_first for this chunk ----
    // wave `quad` owns rows [quad*64, quad*64+64); lane owns cols [4*lane, 4*lane+4).
    // 8 independent float4 loads batched per iteration -> 128 B/thread in flight.
    size_t rowbase = (b == 0) ? (size_t)A_N * 65536 : (size_t)(b - 1) * 65536;
    int quad = t >> 6, lane = t & 63;
    const float4* Wb4 = (const float4*)(Wef + rowbase) + (size_t)quad*64*64 + lane;
    const float*  sgw = sg + quad*64;
    float4 acc = {0.f, 0.f, 0.f, 0.f};
    #pragma unroll
    for (int it = 0; it < 8; ++it) {
        float4 v0 = Wb4[(it*8+0)*64];
        float4 v1 = Wb4[(it*8+1)*64];
        float4 v2 = Wb4[(it*8+2)*64];
        float4 v3 = Wb4[(it*8+3)*64];
        float4 v4 = Wb4[(it*8+4)*64];
        float4 v5 = Wb4[(it*8+5)*64];
        float4 v6 = Wb4[(it*8+6)*64];
        float4 v7 = Wb4[(it*8+7)*64];
        float g0 = sgw[it*8+0], g1 = sgw[it*8+1], g2 = sgw[it*8+2], g3 = sgw[it*8+3];
        float g4 = sgw[it*8+4], g5 = sgw[it*8+5], g6 = sgw[it*8+6], g7 = sgw[it*8+7];
        acc.x += g0*v0.x + g1*v1.x + g2*v2.x + g3*v3.x
               + g4*v4.x + g5*v5.x + g6*v6.x + g7*v7.x;
        acc.y += g0*v0.y + g1*v1.y + g2*v2.y + g3*v3.y
               + g4*v4.y + g5*v5.y + g6*v6.y + g7*v7.y;
        acc.z += g0*v0.z + g1*v1.z + g2*v2.z + g3*v3.z
               + g4*v4.z + g5*v5.z + g6*v6.z + g7*v7.z;
        acc.w += g0*v0.w + g1*v1.w + g2*v2.w + g3*v3.w
               + g4*v4.w + g5*v5.w + g6*v6.w + g7*v7.w;
    }
    sacc[quad][lane*4 + 0] = acc.x;
    sacc[quad][lane*4 + 1] = acc.y;
    sacc[quad][lane*4 + 2] = acc.z;
    sacc[quad][lane*4 + 3] = acc.w;
    __syncthreads();
    part[b*256 + t] = sacc[0][t] + sacc[1][t] + sacc[2][t] + sacc[3][t];
}

// ---- kernel 2: reduce part[2049][256] -> part2[64][256], skipping masked ----
__global__ __launch_bounds__(256) void k_red(const int* __restrict__ Xm,
                                             float* __restrict__ ws)
{
    int r = blockIdx.x, t = threadIdx.x;
    float acc = 0.f;
    for (int b = r; b < NCH; b += 64) {
        if (b == 0 || Xm[b-1] != 0) acc += ws[PART_OFF + b*256 + t];
    }
    ws[PART2_OFF + r*256 + t] = acc;
}

// ---- kernel 3: end stack + final combine (1 block x 1024) ----
__global__ __launch_bounds__(1024) void k_end(
    const float* __restrict__ bef, const float* __restrict__ Wer,
    const float* __restrict__ ber, const float* __restrict__ Weo,
    const float* __restrict__ beo, const float* __restrict__ lw,
    float* __restrict__ out, float* __restrict__ ws)
{
    __shared__ float sx[256];
    __shared__ float racc[4][256];
    __shared__ float red0[1024], red1[1024];
    __shared__ float endraw[4][2];
    int tid = threadIdx.x;
    int q = tid >> 8, t = tid & 255;

    // finish reduce: part2[64][256] -> acc[256], /gsum, bias, relu
    float acc = 0.f;
    #pragma unroll
    for (int j = 0; j < 16; ++j) acc += ws[PART2_OFF + (q*16 + j)*256 + t];
    racc[q][t] = acc;
    __syncthreads();
    float gsum = ws[GSUM_OFF];
    if (tid < 256) {
        float v = racc[0][t] + racc[1][t] + racc[2][t] + racc[3][t];
        sx[t] = fmaxf(v / gsum + bef[t], 0.f);
    }
    __syncthreads();

    #define HEAD_G(W2, B2, SCALE, DEST)                                         \
    {                                                                           \
        if (tid < 256) { red0[tid] = sx[tid]*(W2)[2*tid]; red1[tid] = sx[tid]*(W2)[2*tid+1]; } \
        __syncthreads();                                                        \
        for (int s = 128; s > 0; s >>= 1) {                                     \
            if (tid < s) { red0[tid] += red0[tid+s]; red1[tid] += red1[tid+s]; }\
            __syncthreads();                                                    \
        }                                                                       \
        if (tid == 0) {                                                         \
            float o0 = red0[0] + (B2)[0], o1 = red1[0] + (B2)[1];               \
            float m  = fmaxf(o0, o1);                                           \
            float e0 = expf(o0 - m), e1 = expf(o1 - m);                         \
            float inv = (SCALE) / (e0 + e1);                                    \
            (DEST)[0] = e0 * inv; (DEST)[1] = e1 * inv;                         \
        }                                                                       \
        __syncthreads();                                                        \
    }

    HEAD_G(Weo, beo, lw[2052], &endraw[0][0]);
    for (int i = 0; i < 3; ++i) {
        // K-split 4-way, deep unroll for load overlap (L3-warm after k_main)
        const float* Wq = Wer + i*65536 + (q*64)*256;
        float a2 = 0.f;
        #pragma unroll 16
        for (int k = 0; k < 64; ++k) a2 += sx[q*64 + k] * Wq[k*256 + t];
        racc[q][t] = a2;
        __syncthreads();
        if (tid < 256) {
            float v = racc[0][t] + racc[1][t] + racc[2][t] + racc[3][t];
            sx[t] = fmaxf(v + ber[i*256 + t], 0.f);
        }
        __syncthreads();
        HEAD_G(Weo + (i+1)*512, beo + (i+1)*2, lw[2053 + i], &endraw[i+1][0]);
    }

    // rescale all rows by 1/wsum, accumulate final logit
    float invw = 1.f / ws[WSUM_OFF];
    float s0 = 0.f, s1 = 0.f;
    for (int i = tid; i < NLAYERS; i += 1024) {
        float v0, v1;
        if (i >= 2052 && i < 2056) { v0 = endraw[i-2052][0]; v1 = endraw[i-2052][1]; }
        else                        { v0 = out[2 + 2*i];      v1 = out[2 + 2*i + 1]; }
        v0 *= invw; v1 *= invw;
        out[2 + 2*i]     = v0;
        out[2 + 2*i + 1] = v1;
        s0 += v0; s1 += v1;
    }
    red0[tid] = s0; red1[tid] = s1; __syncthreads();
    for (int s = 512; s > 0; s >>= 1) {
        if (tid < s) { red0[tid] += red0[tid+s]; red1[tid] += red1[tid+s]; }
        __syncthreads();
    }
    if (tid == 0) { out[0] = red0[0]; out[1] = red1[0]; }
}

extern "C" void kernel_launch(void* const* d_in, const int* in_sizes, int n_in,
                              void* d_out, int out_size, void* d_ws, size_t ws_size,
                              hipStream_t stream)
{
    const float* X    = (const float*)d_in[0];
    const int*   Xm   = (const int*)  d_in[1];
    const float* bfv  = (const float*)d_in[2];
    const float* Wbf  = (const float*)d_in[3];
    const float* bbf  = (const float*)d_in[4];
    const float* Wbr  = (const float*)d_in[5];
    const float* bbr  = (const float*)d_in[6];
    const float* Wbo  = (const float*)d_in[7];
    const float* bbo  = (const float*)d_in[8];
    const float* Wm   = (const float*)d_in[9];
    const float* bm   = (const float*)d_in[10];
    const float* Wmo  = (const float*)d_in[11];
    const float* bmo  = (const float*)d_in[12];
    const float* Wa   = (const float*)d_in[13];
    const float* ba   = (const float*)d_in[14];
    const float* Wao  = (const float*)d_in[15];
    const float* bao  = (const float*)d_in[16];
    const float* Wef  = (const float*)d_in[17];
    const float* bef  = (const float*)d_in[18];
    const float* Wer  = (const float*)d_in[19];
    const float* ber  = (const float*)d_in[20];
    const float* Weo  = (const float*)d_in[21];
    const float* beo  = (const float*)d_in[22];
    const float* lw   = (const float*)d_in[23];
    float* out = (float*)d_out;
    float* wsf = (float*)d_ws;

    k_main<<<NCH, 256, 0, stream>>>(X, Xm, bfv, Wbf, bbf, Wbr, bbr, Wbo, bbo,
                                    Wm, bm, Wmo, bmo, Wa, ba, Wao, bao,
                                    Wef, lw, Wer, Weo, bef, ber, out, wsf);
    k_red<<<64, 256, 0, stream>>>(Xm, wsf);
    k_end<<<1, 1024, 0, stream>>>(bef, Wer, ber, Weo, beo, lw, out, wsf);
}